// Round 5
// baseline (3453.482 us; speedup 1.0000x reference)
//
#include <hip/hip_runtime.h>

#define N_PTS 8192
#define R2F 0.015625f   // R*R, exactly representable

// Union: selection phase (u32 keys for all N points) overlaps compute phase
// (W1/x/h1/pm tiles). Keeps static LDS under 64 KB -> 2 blocks/CU.
union SMem {
    struct {
        unsigned int key[N_PTS];   // 32 KB  order-preserving encoded d2
        unsigned int red[8];       // wave partial minima + broadcast slot
    } sel;
    struct {
        float W1s[67][64];         // 16.75 KB
        float xs[64][64];          // 16 KB
        float h1[64][64];          // 16 KB
        float pm[16][128];         // 8 KB
    } cmp;
};

__global__ __launch_bounds__(256) void fused_all(const float* __restrict__ x,
                                                 const float* __restrict__ pos,
                                                 const float* __restrict__ W1,
                                                 const float* __restrict__ b1,
                                                 const float* __restrict__ W2,
                                                 const float* __restrict__ b2,
                                                 const float* __restrict__ Wg,
                                                 const float* __restrict__ bg,
                                                 float* __restrict__ out) {
    __shared__ SMem  u;
    __shared__ int   selj[64];
    __shared__ float seld2[64];
    __shared__ float relS[64][3];
    __shared__ float aggS[128];
    __shared__ int   minj;
    __shared__ int   nvalidS;

    const int t = threadIdx.x;
    const int i = blockIdx.x;

    const float xi = pos[i * 3 + 0], yi = pos[i * 3 + 1], zi = pos[i * 3 + 2];
    const float sqi = __fadd_rn(__fadd_rn(__fmul_rn(xi, xi), __fmul_rn(yi, yi)),
                                __fmul_rn(zi, zi));

    // ---- phase 1: d2 for ALL j, encoded as order-preserving u32 keys ----
    for (int j = t; j < N_PTS; j += 256) {
        const float xj = pos[j * 3 + 0], yj = pos[j * 3 + 1], zj = pos[j * 3 + 2];
        const float sqj = __fadd_rn(__fadd_rn(__fmul_rn(xj, xj), __fmul_rn(yj, yj)),
                                    __fmul_rn(zj, zj));
        const float dot = __fmaf_rn(zi, zj, __fmaf_rn(yi, yj, __fmul_rn(xi, xj)));
        const float d2  = __fsub_rn(__fadd_rn(sqi, sqj), __fmul_rn(2.0f, dot));
        unsigned int b = __float_as_uint(d2);
        b = (b & 0x80000000u) ? ~b : (b | 0x80000000u);  // monotone total order
        u.sel.key[j] = b;
    }
    __syncthreads();

    // ---- 64 exact argmin extractions == stable top_k by (d2, idx) ----
    for (int s = 0; s < 64; ++s) {
        unsigned int m = 0xFFFFFFFFu;
        for (int j = t; j < N_PTS; j += 256) m = min(m, u.sel.key[j]);
        #pragma unroll
        for (int off = 32; off > 0; off >>= 1)
            m = min(m, (unsigned int)__shfl_down((int)m, off));
        if ((t & 63) == 0) u.sel.red[t >> 6] = m;
        if (t == 0) minj = 0x7FFFFFFF;
        __syncthreads();
        if (t == 0)
            u.sel.red[4] = min(min(u.sel.red[0], u.sel.red[1]),
                               min(u.sel.red[2], u.sel.red[3]));
        __syncthreads();
        const unsigned int mk = u.sel.red[4];
        for (int j = t; j < N_PTS; j += 256)
            if (u.sel.key[j] == mk) atomicMin(&minj, j);  // f32-tie -> lowest idx
        __syncthreads();
        if (t == 0) {
            const int j = minj;
            selj[s] = j;
            u.sel.key[j] = 0xFFFFFFFFu;  // sentinel: never re-selected
            const unsigned int bb = (mk & 0x80000000u) ? (mk ^ 0x80000000u) : ~mk;
            seld2[s] = __uint_as_float(bb);
        }
        __syncthreads();
    }

    // ---- validity = ascending-d2 prefix with d2 <= R^2 (self always in) ----
    if (t == 0) {
        int c = 0;
        while (c < 64 && seld2[c] <= R2F) ++c;
        nvalidS = c;
    }
    __syncthreads();
    const int nvalid = nvalidS;

    // ---- stage W1 + gather neighbor x rows + rel (cmp view of the union) ----
    for (int idx = t; idx < 67 * 64; idx += 256)
        u.cmp.W1s[idx >> 6][idx & 63] = W1[idx];
    if (t < 64) {
        const int j = selj[t];
        relS[t][0] = pos[j * 3 + 0] - xi;
        relS[t][1] = pos[j * 3 + 1] - yi;
        relS[t][2] = pos[j * 3 + 2] - zi;
    }
    for (int v = t; v < 64 * 16; v += 256) {
        const int n = v >> 4, c4 = (v & 15) * 4;
        float4 val = make_float4(0.f, 0.f, 0.f, 0.f);
        if (n < nvalid) val = *(const float4*)&x[selj[n] * 64 + c4];
        *(float4*)&u.cmp.xs[n][c4] = val;
    }
    __syncthreads();

    // ---- phase 2: h1[n][c] = relu(x_j . W1a[:,c] + rel . W1b[:,c] + b1[c]) ----
    {
        const int c = t & 63, q = t >> 6;
        const float w1b0 = u.cmp.W1s[64][c], w1b1 = u.cmp.W1s[65][c],
                    w1b2 = u.cmp.W1s[66][c];
        const float bc = b1[c];
        #pragma unroll
        for (int it = 0; it < 16; ++it) {
            const int n = it * 4 + q;
            float v = 0.0f;
            if (n < nvalid) {
                float acc = 0.0f;
                #pragma unroll 16
                for (int k = 0; k < 64; ++k)
                    acc = __fmaf_rn(u.cmp.xs[n][k], u.cmp.W1s[k][c], acc);
                acc = __fmaf_rn(relS[n][0], w1b0, acc);
                acc = __fmaf_rn(relS[n][1], w1b1, acc);
                acc = __fmaf_rn(relS[n][2], w1b2, acc);
                v = fmaxf(acc + bc, 0.0f);
            }
            u.cmp.h1[n][c] = v;
        }
    }
    __syncthreads();

    // ---- phase 3: h2 = relu(h1 @ W2 + b2); masked max over n -> pm ----
    {
        const int c2b = (t & 15) * 8;
        const int g16 = t >> 4;
        const int nb  = g16 * 4;
        float acc[4][8];
        #pragma unroll
        for (int ni = 0; ni < 4; ++ni)
            #pragma unroll
            for (int k = 0; k < 8; ++k) acc[ni][k] = 0.0f;

        for (int cc = 0; cc < 64; ++cc) {
            const float a0 = u.cmp.h1[nb + 0][cc];
            const float a1 = u.cmp.h1[nb + 1][cc];
            const float a2 = u.cmp.h1[nb + 2][cc];
            const float a3 = u.cmp.h1[nb + 3][cc];
            const float4 w0 = *(const float4*)&W2[cc * 128 + c2b];
            const float4 w1 = *(const float4*)&W2[cc * 128 + c2b + 4];
            const float w[8] = {w0.x, w0.y, w0.z, w0.w, w1.x, w1.y, w1.z, w1.w};
            #pragma unroll
            for (int k = 0; k < 8; ++k) {
                acc[0][k] = __fmaf_rn(a0, w[k], acc[0][k]);
                acc[1][k] = __fmaf_rn(a1, w[k], acc[1][k]);
                acc[2][k] = __fmaf_rn(a2, w[k], acc[2][k]);
                acc[3][k] = __fmaf_rn(a3, w[k], acc[3][k]);
            }
        }
        #pragma unroll
        for (int k = 0; k < 8; ++k) {
            const float bb = b2[c2b + k];
            float mm = 0.0f;  // relu floor; valid set nonempty (self)
            #pragma unroll
            for (int ni = 0; ni < 4; ++ni)
                if (nb + ni < nvalid) mm = fmaxf(mm, acc[ni][k] + bb);
            u.cmp.pm[g16][c2b + k] = mm;
        }
    }
    __syncthreads();

    if (t < 128) {
        float mm = u.cmp.pm[0][t];
        #pragma unroll
        for (int g = 1; g < 16; ++g) mm = fmaxf(mm, u.cmp.pm[g][t]);
        aggS[t] = mm;
    }
    __syncthreads();

    // ---- phase 4: out[i][t] = relu(aggS . Wg[:,t] + bg[t]) ----
    {
        float acc = 0.0f;
        #pragma unroll 8
        for (int k = 0; k < 128; ++k)
            acc = __fmaf_rn(aggS[k], Wg[k * 256 + t], acc);
        out[i * 256 + t] = fmaxf(acc + bg[t], 0.0f);
    }
}

// ---------------------------------------------------------------------------
extern "C" void kernel_launch(void* const* d_in, const int* in_sizes, int n_in,
                              void* d_out, int out_size, void* d_ws, size_t ws_size,
                              hipStream_t stream) {
    const float* x   = (const float*)d_in[0];
    const float* pos = (const float*)d_in[1];
    // d_in[2] = batch (all zeros) — unused
    const float* W1 = (const float*)d_in[3];
    const float* b1 = (const float*)d_in[4];
    const float* W2 = (const float*)d_in[5];
    const float* b2 = (const float*)d_in[6];
    const float* Wg = (const float*)d_in[7];
    const float* bg = (const float*)d_in[8];
    float* out = (float*)d_out;

    fused_all<<<N_PTS, 256, 0, stream>>>(x, pos, W1, b1, W2, b2, Wg, bg, out);
}

// Round 7
// 2065.278 us; speedup vs baseline: 1.6722x; 1.6722x over previous
//
#include <hip/hip_runtime.h>

#define N_PTS 8192
#define R2F 0.015625f   // R*R, exactly representable

// Selection keys (32 KB) die before the compute tiles are born -> union.
// pm (8 KB, phase 3 only) overlays xs (dead after phase 2).
union SelCmp {
    unsigned int key[N_PTS];          // 32 KB
    struct {
        float W1s[67][64];            // 16.75 KB (staged AFTER extraction)
        float xs[64][64];             // 16 KB (phase 2); pm[16][128] overlays it
        float h1[64][64];             // 16 KB
    } c;
};

__global__ __launch_bounds__(256) void fused_all(const float* __restrict__ x,
                                                 const float* __restrict__ pos,
                                                 const float* __restrict__ W1,
                                                 const float* __restrict__ b1,
                                                 const float* __restrict__ W2,
                                                 const float* __restrict__ b2,
                                                 const float* __restrict__ Wg,
                                                 const float* __restrict__ bg,
                                                 float* __restrict__ out) {
    __shared__ SelCmp u;
    __shared__ unsigned int partial[256];   // min of key[32t..32t+31]
    __shared__ unsigned int chunkmin[128];  // min of key[64c..64c+63]
    __shared__ int   selj[64];
    __shared__ float seld2[64];
    __shared__ float relS[64][3];
    __shared__ float aggS[128];
    __shared__ unsigned int redW[4];
    __shared__ unsigned int mkS;
    __shared__ int   minj;
    __shared__ int   jstar;
    __shared__ int   nvalidS;

    const int t = threadIdx.x;
    const int i = blockIdx.x;

    const float xi = pos[i * 3 + 0], yi = pos[i * 3 + 1], zi = pos[i * 3 + 2];
    const float sqi = __fadd_rn(__fadd_rn(__fmul_rn(xi, xi), __fmul_rn(yi, yi)),
                                __fmul_rn(zi, zi));

    // ---- phase 1: d2 for ALL j, encoded as order-preserving u32 keys ----
    for (int j = t; j < N_PTS; j += 256) {
        const float xj = pos[j * 3 + 0], yj = pos[j * 3 + 1], zj = pos[j * 3 + 2];
        const float sqj = __fadd_rn(__fadd_rn(__fmul_rn(xj, xj), __fmul_rn(yj, yj)),
                                    __fmul_rn(zj, zj));
        const float dot = __fmaf_rn(zi, zj, __fmaf_rn(yi, yj, __fmul_rn(xi, xj)));
        const float d2  = __fsub_rn(__fadd_rn(sqi, sqj), __fmul_rn(2.0f, dot));
        unsigned int b = __float_as_uint(d2);
        b = (b & 0x80000000u) ? ~b : (b | 0x80000000u);  // monotone total order
        u.key[j] = b;
    }
    __syncthreads();

    // ---- build 2-level min index: partial (per 32 keys), chunkmin (per 64) ----
    {
        unsigned int pmn = 0xFFFFFFFFu;
        const int base = t * 32;
        for (int k = 0; k < 32; ++k) pmn = min(pmn, u.key[base + k]);
        partial[t] = pmn;
    }
    __syncthreads();
    if (t < 128) chunkmin[t] = min(partial[2 * t], partial[2 * t + 1]);
    __syncthreads();

    // ---- 64 exact argmin extractions == stable top_k by (d2, idx) ----
    // Semantics identical to the proven full-scan version; only the scan is
    // replaced by the chunkmin index (complete: any chunk holding the global
    // min key has chunkmin == mk).
    for (int s = 0; s < 64; ++s) {
        unsigned int m = (t < 128) ? chunkmin[t] : 0xFFFFFFFFu;
        #pragma unroll
        for (int off = 32; off > 0; off >>= 1)
            m = min(m, (unsigned int)__shfl_down((int)m, off));
        if ((t & 63) == 0) redW[t >> 6] = m;
        if (t == 0) minj = 0x7FFFFFFF;
        __syncthreads();
        if (t == 0)
            mkS = min(min(redW[0], redW[1]), min(redW[2], redW[3]));
        __syncthreads();
        const unsigned int mk = mkS;
        if (chunkmin[t >> 1] == mk) {              // my 32-segment's chunk may hold mk
            const int base = t * 32;
            for (int k = 0; k < 32; ++k)
                if (u.key[base + k] == mk) atomicMin(&minj, base + k);
        }
        __syncthreads();
        if (t == 0) {
            const int j = minj;
            jstar = j;
            selj[s] = j;
            u.key[j] = 0xFFFFFFFFu;                // sentinel: never re-selected
            const unsigned int bb = (mk & 0x80000000u) ? (mk ^ 0x80000000u) : ~mk;
            seld2[s] = __uint_as_float(bb);
        }
        __syncthreads();
        if (t == (jstar >> 5)) {                   // sole owner of the 32-segment
            unsigned int pmn = 0xFFFFFFFFu;
            const int base = t * 32;
            for (int k = 0; k < 32; ++k) pmn = min(pmn, u.key[base + k]);
            partial[t] = pmn;
            chunkmin[t >> 1] = min(pmn, partial[t ^ 1]);  // sibling is stable
        }
        __syncthreads();
    }

    // ---- validity = ascending-d2 prefix with d2 <= R^2 (self always in) ----
    if (t == 0) {
        int c = 0;
        while (c < 64 && seld2[c] <= R2F) ++c;
        nvalidS = c;
    }
    __syncthreads();
    const int nvalid = nvalidS;

    // ---- stage W1 + gather neighbor x rows + rel (cmp view of the union) ----
    for (int idx = t; idx < 67 * 64; idx += 256)
        u.c.W1s[idx >> 6][idx & 63] = W1[idx];
    if (t < 64) {
        const int j = selj[t];
        relS[t][0] = pos[j * 3 + 0] - xi;
        relS[t][1] = pos[j * 3 + 1] - yi;
        relS[t][2] = pos[j * 3 + 2] - zi;
    }
    for (int v = t; v < 64 * 16; v += 256) {
        const int n = v >> 4, c4 = (v & 15) * 4;
        float4 val = make_float4(0.f, 0.f, 0.f, 0.f);
        if (n < nvalid) val = *(const float4*)&x[selj[n] * 64 + c4];
        *(float4*)&u.c.xs[n][c4] = val;
    }
    __syncthreads();

    // ---- phase 2: h1[n][c] = relu(x_j . W1a[:,c] + rel . W1b[:,c] + b1[c]) ----
    {
        const int c = t & 63, q = t >> 6;
        const float w1b0 = u.c.W1s[64][c], w1b1 = u.c.W1s[65][c],
                    w1b2 = u.c.W1s[66][c];
        const float bc = b1[c];
        #pragma unroll
        for (int it = 0; it < 16; ++it) {
            const int n = it * 4 + q;
            float v = 0.0f;
            if (n < nvalid) {
                float acc = 0.0f;
                #pragma unroll 16
                for (int k = 0; k < 64; ++k)
                    acc = __fmaf_rn(u.c.xs[n][k], u.c.W1s[k][c], acc);
                acc = __fmaf_rn(relS[n][0], w1b0, acc);
                acc = __fmaf_rn(relS[n][1], w1b1, acc);
                acc = __fmaf_rn(relS[n][2], w1b2, acc);
                v = fmaxf(acc + bc, 0.0f);
            }
            u.c.h1[n][c] = v;
        }
    }
    __syncthreads();

    // ---- phase 3: h2 = relu(h1 @ W2 + b2); masked max over n -> pm ----
    // pm overlays xs (dead after phase 2; barrier above separates them).
    float (*pm)[128] = (float (*)[128]) & u.c.xs[0][0];
    {
        const int c2b = (t & 15) * 8;
        const int g16 = t >> 4;
        const int nb  = g16 * 4;
        float acc[4][8];
        #pragma unroll
        for (int ni = 0; ni < 4; ++ni)
            #pragma unroll
            for (int k = 0; k < 8; ++k) acc[ni][k] = 0.0f;

        for (int cc = 0; cc < 64; ++cc) {
            const float a0 = u.c.h1[nb + 0][cc];
            const float a1 = u.c.h1[nb + 1][cc];
            const float a2 = u.c.h1[nb + 2][cc];
            const float a3 = u.c.h1[nb + 3][cc];
            const float4 w0 = *(const float4*)&W2[cc * 128 + c2b];
            const float4 w1 = *(const float4*)&W2[cc * 128 + c2b + 4];
            const float wv[8] = {w0.x, w0.y, w0.z, w0.w, w1.x, w1.y, w1.z, w1.w};
            #pragma unroll
            for (int k = 0; k < 8; ++k) {
                acc[0][k] = __fmaf_rn(a0, wv[k], acc[0][k]);
                acc[1][k] = __fmaf_rn(a1, wv[k], acc[1][k]);
                acc[2][k] = __fmaf_rn(a2, wv[k], acc[2][k]);
                acc[3][k] = __fmaf_rn(a3, wv[k], acc[3][k]);
            }
        }
        #pragma unroll
        for (int k = 0; k < 8; ++k) {
            const float bb = b2[c2b + k];
            float mm = 0.0f;  // relu floor; valid set nonempty (self)
            #pragma unroll
            for (int ni = 0; ni < 4; ++ni)
                if (nb + ni < nvalid) mm = fmaxf(mm, acc[ni][k] + bb);
            pm[g16][c2b + k] = mm;
        }
    }
    __syncthreads();

    if (t < 128) {
        float mm = pm[0][t];
        #pragma unroll
        for (int g = 1; g < 16; ++g) mm = fmaxf(mm, pm[g][t]);
        aggS[t] = mm;
    }
    __syncthreads();

    // ---- phase 4: out[i][t] = relu(aggS . Wg[:,t] + bg[t]) ----
    {
        float acc = 0.0f;
        #pragma unroll 8
        for (int k = 0; k < 128; ++k)
            acc = __fmaf_rn(aggS[k], Wg[k * 256 + t], acc);
        out[i * 256 + t] = fmaxf(acc + bg[t], 0.0f);
    }
}

// ---------------------------------------------------------------------------
extern "C" void kernel_launch(void* const* d_in, const int* in_sizes, int n_in,
                              void* d_out, int out_size, void* d_ws, size_t ws_size,
                              hipStream_t stream) {
    const float* x   = (const float*)d_in[0];
    const float* pos = (const float*)d_in[1];
    // d_in[2] = batch (all zeros) — unused
    const float* W1 = (const float*)d_in[3];
    const float* b1 = (const float*)d_in[4];
    const float* W2 = (const float*)d_in[5];
    const float* b2 = (const float*)d_in[6];
    const float* Wg = (const float*)d_in[7];
    const float* bg = (const float*)d_in[8];
    float* out = (float*)d_out;

    fused_all<<<N_PTS, 256, 0, stream>>>(x, pos, W1, b1, W2, b2, Wg, bg, out);
}

// Round 8
// 1221.361 us; speedup vs baseline: 2.8276x; 1.6910x over previous
//
#include <hip/hip_runtime.h>

#define N_PTS 8192
#define R2F 0.015625f   // R*R, exactly representable

// mb/mj (per-wave sorted top-64 lists) die before W1s is staged -> union.
union U0 {
    struct { unsigned mb[4][64]; unsigned mj[4][64]; } s;  // 2 KB
    float W1s[67][64];                                     // 16.75 KB
};

__global__ __launch_bounds__(256) void fused_all(const float* __restrict__ x,
                                                 const float* __restrict__ pos,
                                                 const float* __restrict__ W1,
                                                 const float* __restrict__ b1,
                                                 const float* __restrict__ W2,
                                                 const float* __restrict__ b2,
                                                 const float* __restrict__ Wg,
                                                 const float* __restrict__ bg,
                                                 float* __restrict__ out) {
    __shared__ U0    u0;
    __shared__ float xs[64][64];     // 16 KB (phase 2); pm[16][128] overlays it
    __shared__ float h1[64][64];     // 16 KB
    __shared__ unsigned selb[64];
    __shared__ int   selj[64];
    __shared__ float relS[64][3];
    __shared__ float aggS[128];
    __shared__ int   nvalidS;

    const int t    = threadIdx.x;
    const int lane = t & 63;
    const int w    = t >> 6;         // wave id; owns quarter j in [2048w, 2048w+2048)
    const int qb   = w << 11;
    const int i    = blockIdx.x;

    const float xi = pos[i * 3 + 0], yi = pos[i * 3 + 1], zi = pos[i * 3 + 2];
    const float sqi = __fadd_rn(__fadd_rn(__fmul_rn(xi, xi), __fmul_rn(yi, yi)),
                                __fmul_rn(zi, zi));

    // ---- phase 1: d2 keys for this wave's quarter, register-resident ----
    // lane's slots: j = qb + lane + 64*k, k = 0..31 (coalesced pos reads)
    unsigned kb[32];
    #pragma unroll
    for (int k = 0; k < 32; ++k) {
        const int j = qb + lane + (k << 6);
        const float xj = pos[j * 3 + 0], yj = pos[j * 3 + 1], zj = pos[j * 3 + 2];
        const float sqj = __fadd_rn(__fadd_rn(__fmul_rn(xj, xj), __fmul_rn(yj, yj)),
                                    __fmul_rn(zj, zj));
        const float dot = __fmaf_rn(zi, zj, __fmaf_rn(yi, yj, __fmul_rn(xi, xj)));
        const float d2  = __fsub_rn(__fadd_rn(sqi, sqj), __fmul_rn(2.0f, dot));
        unsigned b = __float_as_uint(d2);
        kb[k] = (b & 0x80000000u) ? ~b : (b | 0x80000000u);  // monotone total order
    }

    // ---- per-wave: 64 sequential (b, j)-argmin extractions, wave-sync only ----
    unsigned removed = 0u;
    for (int s = 0; s < 64; ++s) {
        unsigned lb = 0xFFFFFFFFu;
        int      lj = 0x7FFFFFFF;
        #pragma unroll
        for (int k = 0; k < 32; ++k) {
            if (!(removed & (1u << k))) {
                const unsigned b = kb[k];
                if (b < lb) { lb = b; lj = qb + lane + (k << 6); }  // asc j: first kept
            }
        }
        unsigned rb = lb;
        int      rj = lj;
        #pragma unroll
        for (int off = 32; off > 0; off >>= 1) {
            const unsigned ob = (unsigned)__shfl_down((int)rb, off);
            const int      oj = __shfl_down(rj, off);
            if (ob < rb || (ob == rb && oj < rj)) { rb = ob; rj = oj; }
        }
        const unsigned wb = (unsigned)__shfl((int)rb, 0);
        const int      wj = __shfl(rj, 0);
        if (lane == 0) { u0.s.mb[w][s] = wb; u0.s.mj[w][s] = (unsigned)wj; }
        if (lb == wb && lj == wj)                         // unique owner lane
            removed |= 1u << ((wj - qb - lane) >> 6);
    }
    __syncthreads();

    // ---- merge: exact global top-64 by (b, j) via parallel rank ----
    // element p of sorted list w has rank = p + sum over other lists of
    // #elements < (b, j). Unique keys -> bijective ranks 0..255.
    {
        const int p = lane;
        const unsigned be = u0.s.mb[w][p];
        const unsigned je = u0.s.mj[w][p];
        int rank = p;
        #pragma unroll
        for (int d = 1; d < 4; ++d) {
            const int wp = (w + d) & 3;
            int lo = 0;
            #pragma unroll
            for (int st = 32; st > 0; st >>= 1) {
                const int idx = lo + st - 1;
                const unsigned ob = u0.s.mb[wp][idx];
                const unsigned oj = u0.s.mj[wp][idx];
                if (ob < be || (ob == be && oj < je)) lo += st;
            }
            {   // final element check (lower_bound over full 64)
                const unsigned ob = u0.s.mb[wp][lo];
                const unsigned oj = u0.s.mj[wp][lo];
                if (ob < be || (ob == be && oj < je)) lo += 1;
            }
            rank += lo;
        }
        if (rank < 64) { selb[rank] = be; selj[rank] = (int)je; }
    }
    __syncthreads();

    // ---- stage W1 (overwrites mb/mj), gather rel + x rows, nvalid ballot ----
    for (int idx = t; idx < 67 * 64; idx += 256)
        u0.W1s[idx >> 6][idx & 63] = W1[idx];
    if (t < 64) {
        const int j = selj[t];
        relS[t][0] = pos[j * 3 + 0] - xi;
        relS[t][1] = pos[j * 3 + 1] - yi;
        relS[t][2] = pos[j * 3 + 2] - zi;
    }
    for (int v = t; v < 64 * 16; v += 256) {
        const int n = v >> 4, c4 = (v & 15) * 4;   // rows >= nvalid never read
        *(float4*)&xs[n][c4] = *(const float4*)&x[selj[n] * 64 + c4];
    }
    {
        bool ok = false;
        if (t < 64) {
            const unsigned b = selb[t];
            const unsigned db = (b & 0x80000000u) ? (b ^ 0x80000000u) : ~b;
            ok = (__uint_as_float(db) <= R2F);
        }
        const unsigned long long vm = __ballot(ok);   // wave 0 covers t=0..63
        if (t == 0) nvalidS = __popcll(vm);  // d2 ascending -> popcount == prefix
    }
    __syncthreads();
    const int nvalid = nvalidS;

    // ---- phase 2: h1[n][c] = relu(x_j . W1a[:,c] + rel . W1b[:,c] + b1[c]) ----
    {
        const int c = t & 63, q = t >> 6;
        const float w1b0 = u0.W1s[64][c], w1b1 = u0.W1s[65][c], w1b2 = u0.W1s[66][c];
        const float bc = b1[c];
        #pragma unroll
        for (int it = 0; it < 16; ++it) {
            const int n = it * 4 + q;
            float v = 0.0f;
            if (n < nvalid) {
                float acc = 0.0f;
                #pragma unroll 16
                for (int k = 0; k < 64; ++k)
                    acc = __fmaf_rn(xs[n][k], u0.W1s[k][c], acc);
                acc = __fmaf_rn(relS[n][0], w1b0, acc);
                acc = __fmaf_rn(relS[n][1], w1b1, acc);
                acc = __fmaf_rn(relS[n][2], w1b2, acc);
                v = fmaxf(acc + bc, 0.0f);
            }
            h1[n][c] = v;
        }
    }
    __syncthreads();

    // ---- phase 3: h2 = relu(h1 @ W2 + b2); masked max over n -> pm ----
    // pm overlays xs (dead after phase 2; barrier above separates them).
    float (*pm)[128] = (float (*)[128]) & xs[0][0];
    {
        const int c2b = (t & 15) * 8;
        const int g16 = t >> 4;
        const int nb  = g16 * 4;
        float acc[4][8];
        #pragma unroll
        for (int ni = 0; ni < 4; ++ni)
            #pragma unroll
            for (int k = 0; k < 8; ++k) acc[ni][k] = 0.0f;

        for (int cc = 0; cc < 64; ++cc) {
            const float a0 = h1[nb + 0][cc];
            const float a1 = h1[nb + 1][cc];
            const float a2 = h1[nb + 2][cc];
            const float a3 = h1[nb + 3][cc];
            const float4 w0 = *(const float4*)&W2[cc * 128 + c2b];
            const float4 w1 = *(const float4*)&W2[cc * 128 + c2b + 4];
            const float wv[8] = {w0.x, w0.y, w0.z, w0.w, w1.x, w1.y, w1.z, w1.w};
            #pragma unroll
            for (int k = 0; k < 8; ++k) {
                acc[0][k] = __fmaf_rn(a0, wv[k], acc[0][k]);
                acc[1][k] = __fmaf_rn(a1, wv[k], acc[1][k]);
                acc[2][k] = __fmaf_rn(a2, wv[k], acc[2][k]);
                acc[3][k] = __fmaf_rn(a3, wv[k], acc[3][k]);
            }
        }
        #pragma unroll
        for (int k = 0; k < 8; ++k) {
            const float bb = b2[c2b + k];
            float mm = 0.0f;  // relu floor; valid set nonempty (self)
            #pragma unroll
            for (int ni = 0; ni < 4; ++ni)
                if (nb + ni < nvalid) mm = fmaxf(mm, acc[ni][k] + bb);
            pm[g16][c2b + k] = mm;
        }
    }
    __syncthreads();

    if (t < 128) {
        float mm = pm[0][t];
        #pragma unroll
        for (int g = 1; g < 16; ++g) mm = fmaxf(mm, pm[g][t]);
        aggS[t] = mm;
    }
    __syncthreads();

    // ---- phase 4: out[i][t] = relu(aggS . Wg[:,t] + bg[t]) ----
    {
        float acc = 0.0f;
        #pragma unroll 8
        for (int k = 0; k < 128; ++k)
            acc = __fmaf_rn(aggS[k], Wg[k * 256 + t], acc);
        out[i * 256 + t] = fmaxf(acc + bg[t], 0.0f);
    }
}

// ---------------------------------------------------------------------------
extern "C" void kernel_launch(void* const* d_in, const int* in_sizes, int n_in,
                              void* d_out, int out_size, void* d_ws, size_t ws_size,
                              hipStream_t stream) {
    const float* x   = (const float*)d_in[0];
    const float* pos = (const float*)d_in[1];
    // d_in[2] = batch (all zeros) — unused
    const float* W1 = (const float*)d_in[3];
    const float* b1 = (const float*)d_in[4];
    const float* W2 = (const float*)d_in[5];
    const float* b2 = (const float*)d_in[6];
    const float* Wg = (const float*)d_in[7];
    const float* bg = (const float*)d_in[8];
    float* out = (float*)d_out;

    fused_all<<<N_PTS, 256, 0, stream>>>(x, pos, W1, b1, W2, b2, Wg, bg, out);
}